// Round 8
// baseline (78.206 us; speedup 1.0000x reference)
//
#include <hip/hip_runtime.h>
#include <math.h>

#define FD 76
#define FFD 5776
#define BD 16
#define CD 256
#define KD 50
#define AD 3

typedef float f32x2 __attribute__((ext_vector_type(2)));
typedef float f32x4 __attribute__((ext_vector_type(4)));

constexpr int QBLK = 361;                // cells per block (5776 = 16*361)
constexpr int NBLK = 256;                // 16 b x 16 q — exactly 1 block/CU

// ws layout (float offsets)
constexpr int ACC_O  = 0;                // [8]: [3]=lcls, [4]=l2cls (cls-kernel atomics)
constexpr int CNT_O  = 8;                // [1] int match counter
constexpr int LIST_O = 16;               // [1024][2] ints (cA, cls)
constexpr int TREC_O = 2064;             // [800][16] per-(b,k) records (16B aligned)
constexpr int WP_O   = TREC_O + 800*16;  // [256][16] reordered W' (16B aligned)
constexpr int BLK_O  = WP_O + 4096;      // [NBLK*4] per-block loss partials

__device__ __forceinline__ float sigm(float x){ return 1.f/(1.f + expf(-x)); }
__device__ __forceinline__ float clg(float x){ return logf(fmaxf(x, 1e-12f)); }
__device__ __forceinline__ float bce(float o, float t){ return -(t*clg(o) + (1.f-t)*clg(1.f-o)); }

// record layout [16]: 0:tx0 1:tx1 2:ty0 3:ty1 4:c7(0.7*ta|1e30) 5:code 6:txf 7:tyf
//                     8:twl 9:thl 10:scale 11:cls 12..15 pad
__global__ __launch_bounds__(256) void label_kernel(const float* __restrict__ labels,
                                                    const float* __restrict__ cw,
                                                    float* __restrict__ ws){
  if (blockIdx.x == 4){                  // build W'[c][16]: W'[c*16+j] = cw[o(j)*256+c]
    const int c = threadIdx.x;
    #pragma unroll
    for (int j = 0; j < 15; ++j){
      const int o = (j/5)*85 + (j%5);
      ws[WP_O + c*16 + j] = cw[o*CD + c];
    }
    ws[WP_O + c*16 + 15] = 0.f;
    return;
  }
  const int it = blockIdx.x*256 + threadIdx.x;
  if (blockIdx.x == 0 && threadIdx.x < 9){
    if (threadIdx.x < 8) ws[ACC_O + threadIdx.x] = 0.f;
    else ((int*)ws)[CNT_O] = 0;
  }
  if (it >= BD*KD) return;
  const float AWH[9][2] = {{1.25f,1.625f},{2.f,3.75f},{4.125f,2.875f},
                           {3.75f,7.625f},{7.75f,5.625f},{7.375f,14.875f},
                           {14.5f,11.25f},{19.5f,24.75f},{46.625f,40.75f}};
  const float* l = labels + it*5;
  const float cls = l[0], x = l[1], y = l[2], w = l[3], h = l[4];
  const bool valid = (cls + x + y + w + h) > 0.f;
  const float tx = x*FD, ty = y*FD, tw = w*FD, th = h*FD;
  const float ta = tw*th;
  float bestv = -1.f; int best = 0;
  #pragma unroll
  for (int n = 0; n < 9; ++n){
    const float mw = fminf(tw, AWH[n][0]), mh = fminf(th, AWH[n][1]);
    const float inter = (mw > 0.f && mh > 0.f) ? mw*mh : 0.f;
    const float iou = inter / (ta + AWH[n][0]*AWH[n][1] - inter);
    if (iou > bestv){ bestv = iou; best = n; }
  }
  const int bn = best % 3;
  const bool match = valid && (best < 3);
  const int ii = (int)tx, jj = (int)ty;
  const bool inb = (ii >= 0 && ii < FD && jj >= 0 && jj < FD);
  const float code = (match && inb) ? (float)(bn*FFD + jj*FD + ii) : -1.f;
  const float aw0 = (bn==0)?1.25f:((bn==1)?2.f:4.125f);
  const float aw1 = (bn==0)?1.625f:((bn==1)?3.75f:2.875f);
  float* r = ws + TREC_O + it*16;
  f32x4 r0 = {tx - tw*0.5f, tx + tw*0.5f, ty - th*0.5f, ty + th*0.5f};
  f32x4 r1 = {valid ? 0.7f*ta : 1e30f, code, tx - floorf(tx), ty - floorf(ty)};
  f32x4 r2 = {logf(tw/aw0 + 1e-16f), logf(th/aw1 + 1e-16f),
              sqrtf(2.f - ta/(float)(FD*FD)), cls};
  f32x4 r3 = {0.f, 0.f, 0.f, 0.f};
  *(f32x4*)(r+0) = r0; *(f32x4*)(r+4) = r1; *(f32x4*)(r+8) = r2; *(f32x4*)(r+12) = r3;
}

// ---------------- fused conv + epilogue: 1 cell/thread, sequential row stream ---------
// 256 blocks x 384 threads = 1 block/CU. Block (b, q) covers cells [q*361, q*361+361)
// of batch b; the 16 q-blocks of one b live on the same XCD (bid%8 == b/2) and stream
// the SAME channel rows near-simultaneously -> aggregate-sequential DRAM traffic,
// shared pages/lines. acc[15] in registers; no LDS/barriers in the hot loop.
__global__ __launch_bounds__(384) void fused_kernel(const float* __restrict__ xin,
    const float* __restrict__ wp, const float* __restrict__ cb,
    float* __restrict__ ws, const float* __restrict__ trecg){
  __shared__ __align__(16) float trec[800];    // this batch's 50 records
  __shared__ float redc[24];
  const int tid  = threadIdx.x;
  const int wv   = tid >> 6;
  const int lane = tid & 63;
  const int bid  = blockIdx.x;
  const int b = ((bid & 7) << 1) | ((bid >> 3) & 1);  // XCD bid%8 hosts b in {2x,2x+1}
  const int q = bid >> 4;
  const int hw0 = q * QBLK;

  if (tid < 200) ((f32x4*)trec)[tid] = ((const f32x4*)(trecg + b*800))[tid];
  __syncthreads();

  const bool act = (tid < QBLK);
  const int  hw  = hw0 + (act ? tid : 0);
  const float* xrow = xin + (size_t)b*CD*FFD + hw;

  float acc[15];
  #pragma unroll
  for (int j = 0; j < 15; ++j) acc[j] = 0.f;

  if (act){
    for (int c0 = 0; c0 < CD; c0 += 16){
      float xr[16];
      #pragma unroll
      for (int i = 0; i < 16; ++i)            // 16 independent 1444B-coalesced loads
        xr[i] = xrow[(size_t)(c0 + i)*FFD];
      #pragma unroll
      for (int i = 0; i < 16; ++i){
        const float* wr = wp + (c0 + i)*16;   // uniform -> s_load (scalar cache)
        #pragma unroll
        for (int j = 0; j < 15; ++j) acc[j] += wr[j]*xr[i];
      }
    }
  }

  // ---- per-thread epilogue: 3 anchors share one 50-record k-loop ----
  float lxy = 0.f, lwh = 0.f, lobj = 0.f, l2p = 0.f;
  if (act){
    const int hh = hw / FD, wc = hw - hh*FD;
    float v[3][5];
    #pragma unroll
    for (int a = 0; a < 3; ++a)
      #pragma unroll
      for (int jj = 0; jj < 5; ++jj)
        v[a][jj] = acc[a*5 + jj] + cb[a*85 + jj];

    const float MW0[3] = {1.25f, 2.f, 4.125f};
    const float MW1[3] = {1.625f, 3.75f, 2.875f};
    float sx[3], sy[3], so[3], pxa[3], pxb[3], pya[3], pyb[3], s7[3], code[3], mx[3];
    int ks[3];
    #pragma unroll
    for (int a = 0; a < 3; ++a){
      sx[a] = sigm(v[a][0]); sy[a] = sigm(v[a][1]); so[a] = sigm(v[a][4]);
      const float pw = expf(v[a][2])*MW0[a], ph = expf(v[a][3])*MW1[a];
      pxa[a] = sx[a] + wc - pw*0.5f; pxb[a] = sx[a] + wc + pw*0.5f;
      pya[a] = sy[a] + hh - ph*0.5f; pyb[a] = sy[a] + hh + ph*0.5f;
      s7[a]  = 0.7f*pw*ph;
      code[a] = (float)(a*FFD + hw);
      mx[a] = -1e30f; ks[a] = -1;
    }
    for (int k = 0; k < KD; ++k){
      const f32x4 rA = *(const f32x4*)&trec[k*16];      // tx0 tx1 ty0 ty1
      const f32x2 rB = *(const f32x2*)&trec[k*16 + 4];  // c7, code
      #pragma unroll
      for (int a = 0; a < 3; ++a){
        const float dx = fminf(pxb[a], rA.y) - fmaxf(pxa[a], rA.x);
        const float dy = fminf(pyb[a], rA.w) - fmaxf(pya[a], rA.z);
        const float inter = fmaxf(dx, 0.f)*fmaxf(dy, 0.f);
        mx[a] = fmaxf(mx[a], 1.7f*inter - rB.x);
        ks[a] = (rB.y == code[a]) ? k : ks[a];
      }
    }
    #pragma unroll
    for (int a = 0; a < 3; ++a){
      if (ks[a] >= 0){
        const float txf = trec[ks[a]*16+6], tyf = trec[ks[a]*16+7];
        const float twl = trec[ks[a]*16+8], thl = trec[ks[a]*16+9];
        const float sc  = trec[ks[a]*16+10], sc2 = sc*sc;
        lxy += sc2*(bce(sx[a], txf) + bce(sy[a], tyf));
        l2p += (sx[a]-txf)*(sx[a]-txf) + (sy[a]-tyf)*(sy[a]-tyf);
        const float d0 = v[a][2]-twl, d1 = v[a][3]-thl;
        lwh += 0.5f*sc2*(d0*d0 + d1*d1);
        l2p += sc2*(d0*d0 + d1*d1);
        lobj += -clg(so[a]); l2p += (so[a]-1.f)*(so[a]-1.f);
        const int pos = atomicAdd((int*)ws + CNT_O, 1);
        if (pos < 1024){ ((int*)ws)[LIST_O + pos*2] = (b*AD + a)*FFD + hw;
                         ((int*)ws)[LIST_O + pos*2 + 1] = (int)trec[ks[a]*16+11]; }
      } else if (!(mx[a] > s7[a])){ lobj += -clg(1.f - so[a]); l2p += so[a]*so[a]; }
    }
  }

  #pragma unroll
  for (int o = 32; o > 0; o >>= 1){
    lxy  += __shfl_down(lxy,  o, 64);
    lwh  += __shfl_down(lwh,  o, 64);
    lobj += __shfl_down(lobj, o, 64);
    l2p  += __shfl_down(l2p,  o, 64);
  }
  __syncthreads();
  if (lane == 0){
    redc[wv*4+0] = lxy; redc[wv*4+1] = lwh; redc[wv*4+2] = lobj; redc[wv*4+3] = l2p;
  }
  __syncthreads();
  if (tid < 4){
    float s = 0.f;
    #pragma unroll
    for (int w = 0; w < 6; ++w) s += redc[w*4 + tid];
    ws[BLK_O + bid*4 + tid] = s;
  }
}

// ---------------- cls kernel: 80 channels at matched cells only -----------------------
__global__ __launch_bounds__(128) void cls_kernel(const float* __restrict__ xin,
    const float* __restrict__ cw, const float* __restrict__ cb, float* __restrict__ ws){
  const int cnt = ((const int*)ws)[CNT_O];
  if ((int)blockIdx.x >= cnt) return;
  const int cA  = ((const int*)ws)[LIST_O + blockIdx.x*2];
  const int cls = ((const int*)ws)[LIST_O + blockIdx.x*2 + 1];
  const int b   = cA / (AD*FFD);
  const int rem = cA - b*AD*FFD;
  const int a   = rem / FFD;
  const int hw  = rem - a*FFD;
  __shared__ float xs[256];
  __shared__ float sm[128];
  const int tid = threadIdx.x;
  const float* xb = xin + ((size_t)b*CD)*FFD + hw;
  xs[tid]       = xb[(size_t)tid*FFD];
  xs[tid + 128] = xb[(size_t)(tid + 128)*FFD];
  __syncthreads();
  float lcls = 0.f, l2p = 0.f;
  if (tid < 80){
    const int o = a*85 + 5 + tid;
    const float* wr = cw + o*CD;
    float s = 0.f;
    #pragma unroll 8
    for (int c = 0; c < CD; ++c) s += xs[c]*wr[c];
    const float e = sigm(s + cb[o]);
    const float t = (tid == cls) ? 1.f : 0.f;
    lcls = bce(e, t);
    l2p  = (e - t)*(e - t);
  }
  sm[tid] = lcls; __syncthreads();
  for (int s2 = 64; s2 > 0; s2 >>= 1){ if (tid < s2) sm[tid] += sm[tid+s2]; __syncthreads(); }
  if (tid == 0) atomicAdd(ws + ACC_O + 3, sm[0]);
  __syncthreads();
  sm[tid] = l2p; __syncthreads();
  for (int s2 = 64; s2 > 0; s2 >>= 1){ if (tid < s2) sm[tid] += sm[tid+s2]; __syncthreads(); }
  if (tid == 0) atomicAdd(ws + ACC_O + 4, sm[0]);
}

// ---------------- finalize ------------------------------------------------------------
__global__ __launch_bounds__(256) void fin_kernel(const float* __restrict__ ws,
                                                  float* __restrict__ out){
  __shared__ float sm[256];
  const int tid = threadIdx.x;
  float p[4] = {0,0,0,0};
  for (int i = tid; i < NBLK; i += 256){
    p[0] += ws[BLK_O + i*4 + 0];
    p[1] += ws[BLK_O + i*4 + 1];
    p[2] += ws[BLK_O + i*4 + 2];
    p[3] += ws[BLK_O + i*4 + 3];
  }
  float tot[4];
  #pragma unroll
  for (int r = 0; r < 4; ++r){
    __syncthreads();
    sm[tid] = p[r];
    __syncthreads();
    for (int s = 128; s > 0; s >>= 1){
      if (tid < s) sm[tid] += sm[tid + s];
      __syncthreads();
    }
    tot[r] = sm[0];
  }
  if (tid == 0){
    const float lxy = tot[0], lwh = tot[1], lobj = tot[2];
    const float lcls = ws[ACC_O+3];
    const float l2   = tot[3] + ws[ACC_O+4];
    out[0] = lxy + lwh + lobj + lcls;
    out[1] = lxy; out[2] = lwh; out[3] = lobj; out[4] = lcls; out[5] = l2;
  }
}

extern "C" void kernel_launch(void* const* d_in, const int* in_sizes, int n_in,
                              void* d_out, int out_size, void* d_ws, size_t ws_size,
                              hipStream_t stream){
  const float* xin    = (const float*)d_in[0];
  const float* labels = (const float*)d_in[1];
  const float* cw     = (const float*)d_in[2];
  const float* cb     = (const float*)d_in[3];
  float* out = (float*)d_out;
  float* ws  = (float*)d_ws;

  label_kernel<<<5, 256, 0, stream>>>(labels, cw, ws);
  fused_kernel<<<NBLK, 384, 0, stream>>>(xin, ws + WP_O, cb, ws, ws + TREC_O);
  cls_kernel<<<800, 128, 0, stream>>>(xin, cw, cb, ws);
  fin_kernel<<<1, 256, 0, stream>>>(ws, out);
}